// Round 5
// baseline (421.771 us; speedup 1.0000x reference)
//
#include <hip/hip_runtime.h>
#include <math.h>

#define B_    2
#define NB_   512
#define C_    80
#define FEAT_ 1024
#define FN_   128
#define FC_   128
#define PE_   64
#define G_    16
#define DQ_   64
#define EO_   8
#define NT_   3
#define SCALE_CLAMP_ 4.135166556742356f

typedef __attribute__((ext_vector_type(8))) short bf16x8;
typedef __attribute__((ext_vector_type(4))) float f32x4;

// ---- workspace layout (float offsets) ----
#define O_ROIEMB  ((size_t)0)                                   // 1024*128
#define O_RANKF   (O_ROIEMB + (size_t)(B_*NB_)*FC_)             // 128*128
#define O_RANKIDX (O_RANKF + (size_t)FN_*FC_)                   // B*128*80 (int)
#define O_SSCORE  (O_RANKIDX + (size_t)B_*FN_*C_)               // B*128*80
#define O_SBOX    (O_SSCORE + (size_t)B_*FN_*C_)                // B*128*80*4
#define O_EMB     (O_SBOX + (size_t)B_*FN_*C_*4)                // B*128*80*128
#define O_ATT     (O_EMB + (size_t)B_*FN_*C_*FC_)               // B*128*80*128
#define O_LW      (O_ATT + (size_t)B_*FN_*C_*FC_)               // 80*128*16*128 ushort = 42MB

__device__ __forceinline__ float bf2f(unsigned short u) {
    return __uint_as_float(((unsigned int)u) << 16);
}
__device__ __forceinline__ unsigned short f2bf(float f) {
    unsigned int x = __float_as_uint(f);
    unsigned int r = (x + 0x7fff + ((x >> 16) & 1)) >> 16;   // RNE
    return (unsigned short)r;
}

// 16B-granule swizzle, 64B row (4 granules)
#define EADDR(row, gr)  ((row)*64 + ((((gr) ^ ((row)&3))) << 4))

// ============ roi_emb (blocks 0..7) + rank_feat (block 8), bf16 MFMA ============
__global__ __launch_bounds__(1024) void k_embed(const float* __restrict__ roi_feat,
                                                const float* __restrict__ roi_w,
                                                const float* __restrict__ roi_b,
                                                const float* __restrict__ rank_w,
                                                const float* __restrict__ rank_b,
                                                float* __restrict__ roi_emb,
                                                float* __restrict__ rank_feat)
{
    const int bid = blockIdx.x;
    const bool isRank = (bid == 8);
    const int t = threadIdx.x;
    const int wv = t >> 6, lane = t & 63, lr = lane & 15, lh = lane >> 4;
    const int rt = wv & 7, ct = wv >> 3;
    const float* Wsrc = isRank ? rank_w : roi_w;
    const float* bsrc = isRank ? rank_b : roi_b;
    float* dst = isRank ? rank_feat : (roi_emb + (size_t)bid*FN_*FC_);

    __shared__ char sm[16384];   // A 8KB | W^T 8KB
    const int ri  = t >> 3, kc = (t & 7) * 4;
    const int wj  = t & 127, wk0 = (t >> 7) * 4;

    f32x4 acc0 = {0,0,0,0}, acc1 = {0,0,0,0}, acc2 = {0,0,0,0}, acc3 = {0,0,0,0};

    for (int ks = 0; ks < 32; ++ks) {
        const int k0 = ks * 32;
        // ---- stage A (128 x 32) bf16 swizzled
        float4 av;
        if (!isRank) {
            av = *(const float4*)(roi_feat + (size_t)(bid*128 + ri)*FEAT_ + k0 + kc);
        } else {
            float tmp[4];
            #pragma unroll
            for (int j = 0; j < 4; ++j) {
                int k = k0 + kc + j;
                int kk = (k < 512) ? k : (k - 512);
                float dim = powf(1000.0f, (float)kk * (1.0f/512.0f));
                float dv = (float)ri / dim;
                tmp[j] = (k < 512) ? sinf(dv) : cosf(dv);
            }
            av = make_float4(tmp[0], tmp[1], tmp[2], tmp[3]);
        }
        *(uint2*)(sm + EADDR(ri, kc >> 3) + (kc & 7)*2) =
            make_uint2((unsigned)f2bf(av.x) | ((unsigned)f2bf(av.y) << 16),
                       (unsigned)f2bf(av.z) | ((unsigned)f2bf(av.w) << 16));
        // ---- stage W^T (128 j x 32 k) bf16 swizzled
        #pragma unroll
        for (int s = 0; s < 4; ++s) {
            int k = wk0 + s;
            float wval = Wsrc[(size_t)(k0 + k)*FC_ + wj];
            *(unsigned short*)(sm + 8192 + EADDR(wj, k >> 3) + (k & 7)*2) = f2bf(wval);
        }
        __syncthreads();
        // ---- MFMA: rows rt*16, cols (ct*4+tj)*16
        bf16x8 a = *(const bf16x8*)(sm + EADDR(rt*16 + lr, lh));
        bf16x8 b0 = *(const bf16x8*)(sm + 8192 + EADDR((ct*4+0)*16 + lr, lh));
        bf16x8 b1 = *(const bf16x8*)(sm + 8192 + EADDR((ct*4+1)*16 + lr, lh));
        bf16x8 b2 = *(const bf16x8*)(sm + 8192 + EADDR((ct*4+2)*16 + lr, lh));
        bf16x8 b3 = *(const bf16x8*)(sm + 8192 + EADDR((ct*4+3)*16 + lr, lh));
        acc0 = __builtin_amdgcn_mfma_f32_16x16x32_bf16(a, b0, acc0, 0, 0, 0);
        acc1 = __builtin_amdgcn_mfma_f32_16x16x32_bf16(a, b1, acc1, 0, 0, 0);
        acc2 = __builtin_amdgcn_mfma_f32_16x16x32_bf16(a, b2, acc2, 0, 0, 0);
        acc3 = __builtin_amdgcn_mfma_f32_16x16x32_bf16(a, b3, acc3, 0, 0, 0);
        __syncthreads();
    }
    // ---- epilogue
    #pragma unroll
    for (int tj = 0; tj < 4; ++tj) {
        f32x4 a = (tj == 0) ? acc0 : (tj == 1) ? acc1 : (tj == 2) ? acc2 : acc3;
        int j = (ct*4 + tj)*16 + lr;
        float bv = bsrc[j];
        #pragma unroll
        for (int reg = 0; reg < 4; ++reg) {
            int row = rt*16 + lh*4 + reg;
            dst[(size_t)row*FC_ + j] = a[reg] + bv;
        }
    }
}

// ============ softmax over boxes + stable top-128 rank ============
__global__ __launch_bounds__(512) void k_topk(const float* __restrict__ scores,
                                              int* __restrict__ rank_idx,
                                              float* __restrict__ sorted_score)
{
    int b = blockIdx.x / C_, c = blockIdx.x % C_;
    __shared__ float p[NB_];
    __shared__ float red[NB_];
    int i = threadIdx.x;
    float s = scores[(size_t)(b*NB_ + i)*(C_+1) + c];
    red[i] = s; __syncthreads();
    for (int o = 256; o > 0; o >>= 1) { if (i < o) red[i] = fmaxf(red[i], red[i+o]); __syncthreads(); }
    float mx = red[0]; __syncthreads();
    float e = expf(s - mx);
    red[i] = e; __syncthreads();
    for (int o = 256; o > 0; o >>= 1) { if (i < o) red[i] += red[i+o]; __syncthreads(); }
    float sum = red[0]; __syncthreads();
    float pi = e / sum;
    p[i] = pi; __syncthreads();
    int rank = 0;
    for (int j = 0; j < NB_; ++j) {
        float pj = p[j];
        rank += (pj > pi) || (pj == pi && j < i);
    }
    if (rank < FN_) {
        rank_idx[(size_t)(b*FN_ + rank)*C_ + c] = i;
        sorted_score[(size_t)(b*FN_ + rank)*C_ + c] = pi;
    }
}

// ============ gather emb_feat + refined sorted boxes (8 items/block) ============
__global__ __launch_bounds__(256) void k_gather(const int* __restrict__ rank_idx,
                                                const float* __restrict__ roi_emb,
                                                const float* __restrict__ rank_feat,
                                                const float* __restrict__ pdeltas,
                                                const float* __restrict__ pboxes,
                                                float* __restrict__ emb_feat,
                                                float* __restrict__ sorted_boxes)
{
    const int t = threadIdx.x;
    const int item = blockIdx.x*8 + (t >> 5);
    const int l = t & 31;
    const int c = item % C_;
    const int bn = item / C_;
    const int n = bn & (FN_-1);
    const int b = bn >> 7;
    const int idx = rank_idx[item];
    const int row = b*NB_ + idx;
    float4 ev = *(const float4*)(roi_emb + (size_t)row*FC_ + l*4);
    float4 rv = *(const float4*)(rank_feat + (size_t)n*FC_ + l*4);
    *(float4*)(emb_feat + (size_t)item*FC_ + l*4) =
        make_float4(ev.x+rv.x, ev.y+rv.y, ev.z+rv.z, ev.w+rv.w);
    if (l == 0) {
        float x1 = pboxes[row*4+0], y1 = pboxes[row*4+1], x2 = pboxes[row*4+2], y2 = pboxes[row*4+3];
        float w = x2 - x1, h = y2 - y1;
        float cx = x1 + 0.5f*w, cy = y1 + 0.5f*h;
        const float* dl = pdeltas + (size_t)row*(C_*4) + c*4;
        float dx = dl[0]/10.0f, dy = dl[1]/10.0f;
        float dw = fminf(dl[2]/5.0f, SCALE_CLAMP_);
        float dh = fminf(dl[3]/5.0f, SCALE_CLAMP_);
        float pcx = dx*w + cx, pcy = dy*h + cy;
        float pw = expf(dw)*w, ph = expf(dh)*h;
        float* ob = sorted_boxes + (size_t)item*4;
        ob[0] = pcx - 0.5f*pw; ob[1] = pcy - 0.5f*ph;
        ob[2] = pcx + 0.5f*pw; ob[3] = pcy + 0.5f*ph;
    }
}

// ============ prior w (pre-log, clamped), all 16 groups, bf16 ============
// grid: 80*32 (cl = bid>>5, n-quad = bid&31), 256 threads.
// lw layout: [cl][n][g][m] bf16
__global__ __launch_bounds__(256) void k_pos2(const float* __restrict__ sorted_boxes,
                                              const float* __restrict__ pos_w,
                                              const float* __restrict__ pos_b,
                                              unsigned short* __restrict__ lw,
                                              int b)
{
    const int cl  = blockIdx.x >> 5;
    const int n0  = (blockIdx.x & 31) * 4;
    const int c   = cl;
    const int t   = threadIdx.x;
    const int m   = t & 127;
    const int nh  = t >> 7;

    __shared__ float geomL[FN_][6];
    __shared__ float pwL[PE_*G_];
    __shared__ float pbL[G_];
    __shared__ float sdimL[8];
    __shared__ unsigned short wtile[2*G_*FN_];   // 8 KB

    for (int i = t; i < PE_*G_; i += 256) pwL[i] = pos_w[i];
    if (t < G_) pbL[t] = pos_b[t];
    if (t >= 16 && t < 24) sdimL[t-16] = 1.0f / powf(1000.0f, 0.125f*(float)(t-16));
    if (t < FN_) {
        const float* bx = sorted_boxes + (((size_t)(b*FN_ + t))*C_ + c)*4;
        float x1 = bx[0], y1 = bx[1], x2 = bx[2], y2 = bx[3];
        float w = x2 - x1 + 1.0f;
        float h = y2 - y1 + 1.0f;
        geomL[t][0] = 0.5f*(x1+x2);
        geomL[t][1] = 0.5f*(y1+y2);
        geomL[t][2] = w;
        geomL[t][3] = h;
        geomL[t][4] = __logf(w);
        geomL[t][5] = __logf(h);
    }
    __syncthreads();

    for (int s = 0; s < 2; ++s) {
        const int n = n0 + s*2 + nh;
        float pm[4];
        {
            float cxn = geomL[n][0], cyn = geomL[n][1];
            float rwn = 1.0f/geomL[n][2], rhn = 1.0f/geomL[n][3];
            pm[0] = __logf(fmaxf(fabsf((cxn - geomL[m][0]) * rwn), 1e-3f)) * 100.0f;
            pm[1] = __logf(fmaxf(fabsf((cyn - geomL[m][1]) * rhn), 1e-3f)) * 100.0f;
            pm[2] = (geomL[n][4] - geomL[m][4]) * 100.0f;
            pm[3] = (geomL[n][5] - geomL[m][5]) * 100.0f;
        }
        float acc[G_];
        #pragma unroll
        for (int g = 0; g < G_; ++g) acc[g] = pbL[g];
        #pragma unroll 1
        for (int r = 0; r < 8; ++r) {
            float inv = sdimL[r];
            #pragma unroll
            for (int f = 0; f < 4; ++f) {
                float a = pm[f] * inv;
                float sv, cv;
                __sincosf(a, &sv, &cv);
                const float* ws_ = &pwL[(f*16 + r)*G_];
                const float* wc_ = &pwL[(f*16 + 8 + r)*G_];
                #pragma unroll
                for (int g = 0; g < G_; ++g) acc[g] += sv*ws_[g] + cv*wc_[g];
            }
        }
        #pragma unroll
        for (int g = 0; g < G_; ++g) {
            float w = fmaxf(fmaxf(acc[g], 0.0f), 1e-6f);
            wtile[(nh*G_ + g)*FN_ + m] = f2bf(w);
        }
        __syncthreads();
        {
            const size_t base4 = ((size_t)(cl*FN_ + n0 + s*2)) * 256;  // float4 units
            const float4* srcv = (const float4*)wtile;
            float4* dstv = (float4*)lw;
            dstv[base4 + t]       = srcv[t];
            dstv[base4 + t + 256] = srcv[t + 256];
        }
        __syncthreads();
    }
}

// ============ MFMA attention per (class, group) ============
#define FT_OFF   0        // ft bf16 [128n][128d] swz   32 KB  (aliased by P later)
#define QL_OFF   32768    // q bf16 [128n][64dq] swz    16 KB
#define KL_OFF   49152    // k bf16 [128m][64dq] swz    16 KB
#define WT_OFF   65536    // W^T bf16 [144r][128d] swz  36 KB (aliased by affL)
#define AFF_OFF  65536    // aff f32 [128][133]         68.1 KB
#define VT_OFF   133632   // V'^T bf16 [16e][128m] swz  4 KB
#define BIAS_OFF 137728   // 128 f32
#define SMEM_SZ  138240

#define ADDR256(row, gr)  ((row)*256 + ((((gr) ^ ((row)&15))) << 4))
#define ADDR128(row, gr)  ((row)*128 + ((((gr) ^ ((row)&7))) << 4))

__global__ __launch_bounds__(1024) void k_attn(const float* __restrict__ emb_feat,
                                               const float* __restrict__ q_w, const float* __restrict__ q_b,
                                               const float* __restrict__ k_w, const float* __restrict__ k_b,
                                               const float* __restrict__ out_w, const float* __restrict__ out_b,
                                               const unsigned short* __restrict__ lw,
                                               float* __restrict__ att,
                                               int b)
{
    const int cl = blockIdx.x >> 4;
    const int g  = blockIdx.x & 15;
    const int c  = cl;
    const int t  = threadIdx.x;
    const int wave = t >> 6;
    const int lane = t & 63;
    const int lr = lane & 15;
    const int lh = lane >> 4;              // 0..3

    __shared__ char smem[SMEM_SZ];
    float* biasL = (float*)(smem + BIAS_OFF);
    float* affF  = (float*)(smem + AFF_OFF);

    // ================= P0: staging =================
    for (int s = 0; s < 4; ++s) {
        int fi = t + s*1024;
        int n  = fi >> 5;
        int d4 = (fi & 31) << 2;
        float4 v = *(const float4*)(emb_feat + ((size_t)(b*FN_ + n)*C_ + c)*FC_ + d4);
        char* dst = smem + FT_OFF + ADDR256(n, d4 >> 3) + ((d4 >> 2) & 1)*8;
        *(uint2*)dst = make_uint2((unsigned)f2bf(v.x) | ((unsigned)f2bf(v.y) << 16),
                                  (unsigned)f2bf(v.z) | ((unsigned)f2bf(v.w) << 16));
    }
    for (int s = 0; s < 2; ++s) {
        int id = t + s*1024;
        int r  = id & 127;
        int g8 = id >> 7;                  // 0..15
        const float* src = (r < 64) ? (q_w + (size_t)(g8*8)*1024 + g*DQ_ + r)
                                    : (k_w + (size_t)(g8*8)*1024 + g*DQ_ + (r-64));
        unsigned short u[8];
        #pragma unroll
        for (int j = 0; j < 8; ++j) u[j] = f2bf(src[(size_t)j*1024]);
        char* dst = smem + WT_OFF + ADDR256(r, g8);
        *(uint4*)dst = make_uint4((unsigned)u[0] | ((unsigned)u[1] << 16),
                                  (unsigned)u[2] | ((unsigned)u[3] << 16),
                                  (unsigned)u[4] | ((unsigned)u[5] << 16),
                                  (unsigned)u[6] | ((unsigned)u[7] << 16));
    }
    if (t < 128) {
        int e  = t & 7;
        int g8 = t >> 3;
        const float* src = out_w + (size_t)g*FC_*EO_ + (size_t)(g8*8)*EO_ + e;
        unsigned short u[8];
        #pragma unroll
        for (int j = 0; j < 8; ++j) u[j] = f2bf(src[(size_t)j*EO_]);
        int r = 128 + e;
        char* dst = smem + WT_OFF + ADDR256(r, g8);
        *(uint4*)dst = make_uint4((unsigned)u[0] | ((unsigned)u[1] << 16),
                                  (unsigned)u[2] | ((unsigned)u[3] << 16),
                                  (unsigned)u[4] | ((unsigned)u[5] << 16),
                                  (unsigned)u[6] | ((unsigned)u[7] << 16));
    }
    if (t >= 256 && t < 512) {
        int i = t - 256;
        *(uint2*)(smem + WT_OFF + 136*256 + i*8) = make_uint2(0u, 0u);
    }
    if (t >= 512 && t < 768) {
        int i = t - 512;
        *(uint2*)(smem + VT_OFF + 8*256 + i*8) = make_uint2(0u, 0u);
    }
    if (t >= 128 && t < 256) {
        int r = t - 128;
        biasL[r] = (r < 64) ? q_b[g*DQ_ + r] : k_b[g*DQ_ + (r-64)];
    }
    __syncthreads();

    // ================= P1: proj MFMA =================
    {
        const int rb = (wave >> 2) * 32;
        const int nb = (wave & 3) * 32;
        f32x4 acc00 = {0,0,0,0}, acc01 = {0,0,0,0}, acc10 = {0,0,0,0}, acc11 = {0,0,0,0};
        f32x4 accV  = {0,0,0,0};
        #pragma unroll
        for (int ks = 0; ks < 4; ++ks) {
            int soff = ((ks*4 + lh) ^ lr) << 4;
            bf16x8 a0 = *(const bf16x8*)(smem + WT_OFF + (rb + lr)*256 + soff);
            bf16x8 a1 = *(const bf16x8*)(smem + WT_OFF + (rb + 16 + lr)*256 + soff);
            bf16x8 b0 = *(const bf16x8*)(smem + FT_OFF + (nb + lr)*256 + soff);
            bf16x8 b1 = *(const bf16x8*)(smem + FT_OFF + (nb + 16 + lr)*256 + soff);
            acc00 = __builtin_amdgcn_mfma_f32_16x16x32_bf16(a0, b0, acc00, 0, 0, 0);
            acc01 = __builtin_amdgcn_mfma_f32_16x16x32_bf16(a0, b1, acc01, 0, 0, 0);
            acc10 = __builtin_amdgcn_mfma_f32_16x16x32_bf16(a1, b0, acc10, 0, 0, 0);
            acc11 = __builtin_amdgcn_mfma_f32_16x16x32_bf16(a1, b1, acc11, 0, 0, 0);
            if (wave < 8) {
                bf16x8 av = *(const bf16x8*)(smem + WT_OFF + (128 + lr)*256 + soff);
                bf16x8 bv = *(const bf16x8*)(smem + FT_OFF + (wave*16 + lr)*256 + soff);
                accV = __builtin_amdgcn_mfma_f32_16x16x32_bf16(av, bv, accV, 0, 0, 0);
            }
        }
        #pragma unroll
        for (int ti = 0; ti < 2; ++ti) {
            #pragma unroll
            for (int tj = 0; tj < 2; ++tj) {
                f32x4 a = (ti == 0) ? (tj == 0 ? acc00 : acc01) : (tj == 0 ? acc10 : acc11);
                int r0 = rb + ti*16 + lh*4;
                int n  = nb + tj*16 + lr;
                float v0 = a[0] + biasL[r0+0];
                float v1 = a[1] + biasL[r0+1];
                float v2 = a[2] + biasL[r0+2];
                float v3 = a[3] + biasL[r0+3];
                int dq0 = r0 & 63;
                int off = (r0 < 64 ? QL_OFF : KL_OFF);
                char* dst = smem + off + ADDR128(n, dq0 >> 3) + ((dq0 >> 2) & 1)*8;
                *(uint2*)dst = make_uint2((unsigned)f2bf(v0) | ((unsigned)f2bf(v1) << 16),
                                          (unsigned)f2bf(v2) | ((unsigned)f2bf(v3) << 16));
            }
        }
        if (wave < 8 && lh < 2) {
            int m = wave*16 + lr;
            #pragma unroll
            for (int reg = 0; reg < 4; ++reg) {
                int e = lh*4 + reg;
                char* dst = smem + VT_OFF + (e)*256 + ((((m >> 3) ^ e)) << 4) + (m & 7)*2;
                *(unsigned short*)dst = f2bf(accV[reg]);
            }
        }
    }
    __syncthreads();

    // ================= P2: aff MFMA =================
    {
        const int nb = (wave >> 2) * 32;
        const int mb = (wave & 3) * 32;
        f32x4 acc00 = {0,0,0,0}, acc01 = {0,0,0,0}, acc10 = {0,0,0,0}, acc11 = {0,0,0,0};
        #pragma unroll
        for (int ks = 0; ks < 2; ++ks) {
            int soff = ((ks*4 + lh) ^ (lr & 7)) << 4;
            bf16x8 a0 = *(const bf16x8*)(smem + QL_OFF + (nb + lr)*128 + soff);
            bf16x8 a1 = *(const bf16x8*)(smem + QL_OFF + (nb + 16 + lr)*128 + soff);
            bf16x8 b0 = *(const bf16x8*)(smem + KL_OFF + (mb + lr)*128 + soff);
            bf16x8 b1 = *(const bf16x8*)(smem + KL_OFF + (mb + 16 + lr)*128 + soff);
            acc00 = __builtin_amdgcn_mfma_f32_16x16x32_bf16(a0, b0, acc00, 0, 0, 0);
            acc01 = __builtin_amdgcn_mfma_f32_16x16x32_bf16(a0, b1, acc01, 0, 0, 0);
            acc10 = __builtin_amdgcn_mfma_f32_16x16x32_bf16(a1, b0, acc10, 0, 0, 0);
            acc11 = __builtin_amdgcn_mfma_f32_16x16x32_bf16(a1, b1, acc11, 0, 0, 0);
        }
        #pragma unroll
        for (int ti = 0; ti < 2; ++ti) {
            #pragma unroll
            for (int tj = 0; tj < 2; ++tj) {
                f32x4 a = (ti == 0) ? (tj == 0 ? acc00 : acc01) : (tj == 0 ? acc10 : acc11);
                int n0 = nb + ti*16 + lh*4;
                int m  = mb + tj*16 + lr;
                #pragma unroll
                for (int reg = 0; reg < 4; ++reg)
                    affF[(n0 + reg)*133 + m] = a[reg];
            }
        }
    }
    __syncthreads();

    // ================= P3: softmax + P bf16 over ft =================
    {
        const int row = t >> 3;
        const int lp  = t & 7;
        const int m0  = lp * 16;
        const unsigned short* lwrow = lw + (((size_t)cl*FN_ + row)*G_ + g)*FN_ + m0;
        float v[16];
        float mx = -INFINITY;
        #pragma unroll
        for (int j = 0; j < 16; ++j) {
            float val = affF[row*133 + m0 + j]*0.125f + __logf(bf2f(lwrow[j]));
            v[j] = val;
            mx = fmaxf(mx, val);
        }
        #pragma unroll
        for (int s = 1; s < 8; s <<= 1) mx = fmaxf(mx, __shfl_xor(mx, s, 8));
        float sum = 0.f;
        #pragma unroll
        for (int j = 0; j < 16; ++j) { v[j] = __expf(v[j] - mx); sum += v[j]; }
        #pragma unroll
        for (int s = 1; s < 8; s <<= 1) sum += __shfl_xor(sum, s, 8);
        float rs = 1.0f / sum;
        unsigned short u[16];
        #pragma unroll
        for (int j = 0; j < 16; ++j) u[j] = f2bf(v[j] * rs);
        char* d0 = smem + FT_OFF + ADDR256(row, lp*2);
        char* d1 = smem + FT_OFF + ADDR256(row, lp*2 + 1);
        *(uint4*)d0 = make_uint4((unsigned)u[0] | ((unsigned)u[1] << 16),
                                 (unsigned)u[2] | ((unsigned)u[3] << 16),
                                 (unsigned)u[4] | ((unsigned)u[5] << 16),
                                 (unsigned)u[6] | ((unsigned)u[7] << 16));
        *(uint4*)d1 = make_uint4((unsigned)u[8]  | ((unsigned)u[9]  << 16),
                                 (unsigned)u[10] | ((unsigned)u[11] << 16),
                                 (unsigned)u[12] | ((unsigned)u[13] << 16),
                                 (unsigned)u[14] | ((unsigned)u[15] << 16));
    }
    __syncthreads();

    // ================= P4: att = P @ V' =================
    if (wave < 8) {
        const int tb = wave * 16;
        f32x4 acc = {0,0,0,0};
        #pragma unroll
        for (int ks = 0; ks < 4; ++ks) {
            int soff = ((ks*4 + lh) ^ lr) << 4;
            bf16x8 a = *(const bf16x8*)(smem + FT_OFF + (tb + lr)*256 + soff);
            bf16x8 bv = *(const bf16x8*)(smem + VT_OFF + lr*256 + soff);
            acc = __builtin_amdgcn_mfma_f32_16x16x32_bf16(a, bv, acc, 0, 0, 0);
        }
        if (lr < 8) {
            float ob = out_b[g*EO_ + lr];
            #pragma unroll
            for (int reg = 0; reg < 4; ++reg) {
                int n = tb + lh*4 + reg;
                att[((size_t)(b*FN_ + n)*C_ + c)*FC_ + g*EO_ + lr] = acc[reg] + ob;
            }
        }
    }
}

// ============ final: 8 items/block, 32 lanes/item ============
__global__ __launch_bounds__(256) void k_final(const float* __restrict__ emb_feat,
                                               const float* __restrict__ att,
                                               const float* __restrict__ logit_w,
                                               const float* __restrict__ logit_b,
                                               const float* __restrict__ sorted_score,
                                               float* __restrict__ out)
{
    __shared__ float lwL[FC_*NT_ + NT_];
    const int t = threadIdx.x;
    for (int i = t; i < FC_*NT_ + NT_; i += 256)
        lwL[i] = (i < FC_*NT_) ? logit_w[i] : logit_b[i - FC_*NT_];
    __syncthreads();
    const int item = blockIdx.x*8 + (t >> 5);
    const int l = t & 31;
    const int d0 = l*4;
    float4 ev = *(const float4*)(emb_feat + (size_t)item*FC_ + d0);
    float4 av = *(const float4*)(att + (size_t)item*FC_ + d0);
    float a0 = fmaxf(ev.x + av.x, 0.f);
    float a1 = fmaxf(ev.y + av.y, 0.f);
    float a2 = fmaxf(ev.z + av.z, 0.f);
    float a3 = fmaxf(ev.w + av.w, 0.f);
    float s0 = a0*lwL[(d0+0)*NT_+0] + a1*lwL[(d0+1)*NT_+0] + a2*lwL[(d0+2)*NT_+0] + a3*lwL[(d0+3)*NT_+0];
    float s1 = a0*lwL[(d0+0)*NT_+1] + a1*lwL[(d0+1)*NT_+1] + a2*lwL[(d0+2)*NT_+1] + a3*lwL[(d0+3)*NT_+1];
    float s2 = a0*lwL[(d0+0)*NT_+2] + a1*lwL[(d0+1)*NT_+2] + a2*lwL[(d0+2)*NT_+2] + a3*lwL[(d0+3)*NT_+2];
    #pragma unroll
    for (int s = 1; s < 32; s <<= 1) {
        s0 += __shfl_xor(s0, s, 32);
        s1 += __shfl_xor(s1, s, 32);
        s2 += __shfl_xor(s2, s, 32);
    }
    if (l < NT_) {
        float lg = (l == 0) ? s0 : (l == 1) ? s1 : s2;
        lg += lwL[FC_*NT_ + l];
        float sg = 1.f / (1.f + expf(-lg));
        out[(size_t)item*NT_ + l] = sg * sorted_score[item];
    }
}

extern "C" void kernel_launch(void* const* d_in, const int* in_sizes, int n_in,
                              void* d_out, int out_size, void* d_ws, size_t ws_size,
                              hipStream_t stream) {
    (void)in_sizes; (void)n_in; (void)out_size; (void)ws_size;
    const float* roi_feat = (const float*)d_in[0];
    const float* scores   = (const float*)d_in[1];
    const float* pdeltas  = (const float*)d_in[2];
    const float* pboxes   = (const float*)d_in[3];
    const float* roi_w    = (const float*)d_in[4];
    const float* roi_b    = (const float*)d_in[5];
    const float* rank_w   = (const float*)d_in[6];
    const float* rank_b   = (const float*)d_in[7];
    const float* logit_w  = (const float*)d_in[8];
    const float* logit_b  = (const float*)d_in[9];
    const float* pos_w    = (const float*)d_in[10];
    const float* pos_b    = (const float*)d_in[11];
    const float* q_w      = (const float*)d_in[12];
    const float* q_b      = (const float*)d_in[13];
    const float* k_w      = (const float*)d_in[14];
    const float* k_b      = (const float*)d_in[15];
    const float* out_w    = (const float*)d_in[16];
    const float* out_b    = (const float*)d_in[17];
    float* ws = (float*)d_ws;

    float* roi_emb      = ws + O_ROIEMB;
    float* rank_feat    = ws + O_RANKF;
    int*   rank_idx     = (int*)(ws + O_RANKIDX);
    float* sorted_score = ws + O_SSCORE;
    float* sorted_boxes = ws + O_SBOX;
    float* emb_feat     = ws + O_EMB;
    float* att          = ws + O_ATT;
    unsigned short* lwb = (unsigned short*)(ws + O_LW);

    k_embed<<<dim3(9), dim3(1024), 0, stream>>>(roi_feat, roi_w, roi_b, rank_w, rank_b,
                                                roi_emb, rank_feat);
    k_topk<<<dim3(B_*C_), dim3(512), 0, stream>>>(scores, rank_idx, sorted_score);
    k_gather<<<dim3(B_*FN_*C_/8), dim3(256), 0, stream>>>(rank_idx, roi_emb, rank_feat,
                                                          pdeltas, pboxes, emb_feat, sorted_boxes);
    for (int b = 0; b < B_; ++b) {
        k_pos2<<<dim3(C_*32), dim3(256), 0, stream>>>(sorted_boxes, pos_w, pos_b, lwb, b);
        k_attn<<<dim3(C_*G_), dim3(1024), 0, stream>>>(emb_feat, q_w, q_b, k_w, k_b,
                                                       out_w, out_b, lwb, att, b);
    }
    k_final<<<dim3(B_*FN_*C_/8), dim3(256), 0, stream>>>(emb_feat, att, logit_w, logit_b,
                                                         sorted_score, d_out ? (float*)d_out : nullptr);
}

// Round 7
// 250.952 us; speedup vs baseline: 1.6807x; 1.6807x over previous
//
#include <hip/hip_runtime.h>
#include <math.h>

#define B_    2
#define NB_   512
#define C_    80
#define FEAT_ 1024
#define FN_   128
#define FC_   128
#define PE_   64
#define G_    16
#define DQ_   64
#define EO_   8
#define NT_   3
#define SCALE_CLAMP_ 4.135166556742356f

typedef __attribute__((ext_vector_type(8))) short bf16x8;
typedef __attribute__((ext_vector_type(4))) float f32x4;

// ---- workspace layout (float offsets) ----
#define O_ROIP    ((size_t)0)                                   // 2*1024*128 (K-half partials)
#define O_RANKP   (O_ROIP + (size_t)2*B_*NB_*FC_)               // 2*128*128
#define O_RANKIDX (O_RANKP + (size_t)2*FN_*FC_)                 // B*128*80 (int)
#define O_SSCORE  (O_RANKIDX + (size_t)B_*FN_*C_)               // B*128*80
#define O_SBOX    (O_SSCORE + (size_t)B_*FN_*C_)                // B*128*80*4
#define O_EMB     (O_SBOX + (size_t)B_*FN_*C_*4)                // B*128*80*128
#define O_ATT     (O_EMB + (size_t)B_*FN_*C_*FC_)               // B*128*80*128
#define O_LW      (O_ATT + (size_t)B_*FN_*C_*FC_)               // 2*80*128*16*128 ushort = 84MB

__device__ __forceinline__ float bf2f(unsigned short u) {
    return __uint_as_float(((unsigned int)u) << 16);
}
__device__ __forceinline__ unsigned short f2bf(float f) {
    unsigned int x = __float_as_uint(f);
    unsigned int r = (x + 0x7fff + ((x >> 16) & 1)) >> 16;   // RNE
    return (unsigned short)r;
}

// ============ embed GEMMs: roi (row-tiles 0..63) + rank (64..71), x2 K-halves ============
// grid 144 = 72 row-tiles * 2 khalves, 256 threads (4 waves), no LDS / no barriers.
// Partials: roiP[kh][1024][128], rankP[kh][128][128]; bias added in kh==0 only.
__global__ __launch_bounds__(256) void k_embed(const float* __restrict__ roi_feat,
                                               const float* __restrict__ roi_w,
                                               const float* __restrict__ roi_b,
                                               const float* __restrict__ rank_w,
                                               const float* __restrict__ rank_b,
                                               float* __restrict__ roiP,
                                               float* __restrict__ rankP)
{
    const int bid = blockIdx.x;
    const int kh  = bid & 1;
    const int rt  = bid >> 1;            // 0..71
    const bool isRank = rt >= 64;
    const int row0 = (isRank ? rt - 64 : rt) * 16;
    const int t = threadIdx.x;
    const int w = t >> 6, lane = t & 63, lr = lane & 15, lh = lane >> 4;
    const int col0 = w * 32;
    const float* W = isRank ? rank_w : roi_w;
    const float* bias = isRank ? rank_b : roi_b;

    const int arow = row0 + lr;
    f32x4 acc0 = {0,0,0,0}, acc1 = {0,0,0,0};

    #pragma unroll 4
    for (int ks = 0; ks < 16; ++ks) {
        const int kb = kh*512 + ks*32 + lh*8;
        bf16x8 af;
        if (!isRank) {
            float4 a0 = *(const float4*)(roi_feat + (size_t)arow*FEAT_ + kb);
            float4 a1 = *(const float4*)(roi_feat + (size_t)arow*FEAT_ + kb + 4);
            af[0] = (short)f2bf(a0.x); af[1] = (short)f2bf(a0.y);
            af[2] = (short)f2bf(a0.z); af[3] = (short)f2bf(a0.w);
            af[4] = (short)f2bf(a1.x); af[5] = (short)f2bf(a1.y);
            af[6] = (short)f2bf(a1.z); af[7] = (short)f2bf(a1.w);
        } else {
            #pragma unroll
            for (int j = 0; j < 8; ++j) {
                int k = kb + j;
                int kk = k & 511;
                float inv = exp2f(-(float)kk * 0.0194644226f);  // log2(1000)/512
                float arg = (float)arow * inv;
                float v = (k < 512) ? __sinf(arg) : __cosf(arg);
                af[j] = (short)f2bf(v);
            }
        }
        bf16x8 bf0, bf1;
        #pragma unroll
        for (int j = 0; j < 8; ++j) {
            const float* wr = W + (size_t)(kb + j)*FC_ + col0 + lr;
            bf0[j] = (short)f2bf(wr[0]);
            bf1[j] = (short)f2bf(wr[16]);
        }
        acc0 = __builtin_amdgcn_mfma_f32_16x16x32_bf16(af, bf0, acc0, 0, 0, 0);
        acc1 = __builtin_amdgcn_mfma_f32_16x16x32_bf16(af, bf1, acc1, 0, 0, 0);
    }
    float* dst = isRank ? (rankP + (size_t)kh*FN_*FC_) : (roiP + (size_t)kh*(B_*NB_)*FC_);
    #pragma unroll
    for (int tile = 0; tile < 2; ++tile) {
        f32x4 a = tile ? acc1 : acc0;
        int col = col0 + tile*16 + lr;
        float bv = (kh == 0) ? bias[col] : 0.0f;
        #pragma unroll
        for (int reg = 0; reg < 4; ++reg) {
            int rr = row0 + lh*4 + reg;
            dst[(size_t)rr*FC_ + col] = a[reg] + bv;
        }
    }
}

// ============ softmax over boxes + stable top-128 rank ============
__global__ __launch_bounds__(512) void k_topk(const float* __restrict__ scores,
                                              int* __restrict__ rank_idx,
                                              float* __restrict__ sorted_score)
{
    int b = blockIdx.x / C_, c = blockIdx.x % C_;
    __shared__ float p[NB_];
    __shared__ float red[NB_];
    int i = threadIdx.x;
    float s = scores[(size_t)(b*NB_ + i)*(C_+1) + c];
    red[i] = s; __syncthreads();
    for (int o = 256; o > 0; o >>= 1) { if (i < o) red[i] = fmaxf(red[i], red[i+o]); __syncthreads(); }
    float mx = red[0]; __syncthreads();
    float e = expf(s - mx);
    red[i] = e; __syncthreads();
    for (int o = 256; o > 0; o >>= 1) { if (i < o) red[i] += red[i+o]; __syncthreads(); }
    float sum = red[0]; __syncthreads();
    float pi = e / sum;
    p[i] = pi; __syncthreads();
    int rank = 0;
    for (int j = 0; j < NB_; ++j) {
        float pj = p[j];
        rank += (pj > pi) || (pj == pi && j < i);
    }
    if (rank < FN_) {
        rank_idx[(size_t)(b*FN_ + rank)*C_ + c] = i;
        sorted_score[(size_t)(b*FN_ + rank)*C_ + c] = pi;
    }
}

// ============ gather emb_feat (sum K-half partials) + refined boxes ============
__global__ __launch_bounds__(256) void k_gather(const int* __restrict__ rank_idx,
                                                const float* __restrict__ roiP,
                                                const float* __restrict__ rankP,
                                                const float* __restrict__ pdeltas,
                                                const float* __restrict__ pboxes,
                                                float* __restrict__ emb_feat,
                                                float* __restrict__ sorted_boxes)
{
    const int t = threadIdx.x;
    const int item = blockIdx.x*8 + (t >> 5);
    const int l = t & 31;
    const int c = item % C_;
    const int bn = item / C_;
    const int n = bn & (FN_-1);
    const int b = bn >> 7;
    const int idx = rank_idx[item];
    const int row = b*NB_ + idx;
    float4 e0 = *(const float4*)(roiP + (size_t)row*FC_ + l*4);
    float4 e1 = *(const float4*)(roiP + (size_t)(B_*NB_ + row)*FC_ + l*4);
    float4 r0 = *(const float4*)(rankP + (size_t)n*FC_ + l*4);
    float4 r1 = *(const float4*)(rankP + (size_t)(FN_ + n)*FC_ + l*4);
    *(float4*)(emb_feat + (size_t)item*FC_ + l*4) =
        make_float4(e0.x+e1.x+r0.x+r1.x, e0.y+e1.y+r0.y+r1.y,
                    e0.z+e1.z+r0.z+r1.z, e0.w+e1.w+r0.w+r1.w);
    if (l == 0) {
        float x1 = pboxes[row*4+0], y1 = pboxes[row*4+1], x2 = pboxes[row*4+2], y2 = pboxes[row*4+3];
        float w = x2 - x1, h = y2 - y1;
        float cx = x1 + 0.5f*w, cy = y1 + 0.5f*h;
        const float* dl = pdeltas + (size_t)row*(C_*4) + c*4;
        float dx = dl[0]/10.0f, dy = dl[1]/10.0f;
        float dw = fminf(dl[2]/5.0f, SCALE_CLAMP_);
        float dh = fminf(dl[3]/5.0f, SCALE_CLAMP_);
        float pcx = dx*w + cx, pcy = dy*h + cy;
        float pw = expf(dw)*w, ph = expf(dh)*h;
        float* ob = sorted_boxes + (size_t)item*4;
        ob[0] = pcx - 0.5f*pw; ob[1] = pcy - 0.5f*ph;
        ob[2] = pcx + 0.5f*pw; ob[3] = pcy + 0.5f*ph;
    }
}

// ============ prior w (pre-log, clamped), all 16 groups, bf16, BOTH batches ============
// grid: B*80*32 (nq = bid&31, cl = (bid>>5)%80, b = (bid>>5)/80), 256 threads.
// lw layout: [b*C+cl][n][g][m] bf16
__global__ __launch_bounds__(256) void k_pos2(const float* __restrict__ sorted_boxes,
                                              const float* __restrict__ pos_w,
                                              const float* __restrict__ pos_b,
                                              unsigned short* __restrict__ lw)
{
    const int nq   = blockIdx.x & 31;
    const int rest = blockIdx.x >> 5;
    const int cl   = rest % C_;
    const int b    = rest / C_;
    const int n0   = nq * 4;
    const int c    = cl;
    const int t    = threadIdx.x;
    const int m    = t & 127;
    const int nh   = t >> 7;

    __shared__ float geomL[FN_][6];
    __shared__ float pwL[PE_*G_];
    __shared__ float pbL[G_];
    __shared__ float sdimL[8];
    __shared__ unsigned short wtile[2*G_*FN_];   // 8 KB

    for (int i = t; i < PE_*G_; i += 256) pwL[i] = pos_w[i];
    if (t < G_) pbL[t] = pos_b[t];
    if (t >= 16 && t < 24) sdimL[t-16] = 1.0f / powf(1000.0f, 0.125f*(float)(t-16));
    if (t < FN_) {
        const float* bx = sorted_boxes + (((size_t)(b*FN_ + t))*C_ + c)*4;
        float x1 = bx[0], y1 = bx[1], x2 = bx[2], y2 = bx[3];
        float w = x2 - x1 + 1.0f;
        float h = y2 - y1 + 1.0f;
        geomL[t][0] = 0.5f*(x1+x2);
        geomL[t][1] = 0.5f*(y1+y2);
        geomL[t][2] = w;
        geomL[t][3] = h;
        geomL[t][4] = __logf(w);
        geomL[t][5] = __logf(h);
    }
    __syncthreads();

    for (int s = 0; s < 2; ++s) {
        const int n = n0 + s*2 + nh;
        float pm[4];
        {
            float cxn = geomL[n][0], cyn = geomL[n][1];
            float rwn = 1.0f/geomL[n][2], rhn = 1.0f/geomL[n][3];
            pm[0] = __logf(fmaxf(fabsf((cxn - geomL[m][0]) * rwn), 1e-3f)) * 100.0f;
            pm[1] = __logf(fmaxf(fabsf((cyn - geomL[m][1]) * rhn), 1e-3f)) * 100.0f;
            pm[2] = (geomL[n][4] - geomL[m][4]) * 100.0f;
            pm[3] = (geomL[n][5] - geomL[m][5]) * 100.0f;
        }
        float acc[G_];
        #pragma unroll
        for (int g = 0; g < G_; ++g) acc[g] = pbL[g];
        #pragma unroll 1
        for (int r = 0; r < 8; ++r) {
            float inv = sdimL[r];
            #pragma unroll
            for (int f = 0; f < 4; ++f) {
                float a = pm[f] * inv;
                float sv, cv;
                __sincosf(a, &sv, &cv);
                const float* ws_ = &pwL[(f*16 + r)*G_];
                const float* wc_ = &pwL[(f*16 + 8 + r)*G_];
                #pragma unroll
                for (int g = 0; g < G_; ++g) acc[g] += sv*ws_[g] + cv*wc_[g];
            }
        }
        #pragma unroll
        for (int g = 0; g < G_; ++g) {
            float w = fmaxf(fmaxf(acc[g], 0.0f), 1e-6f);
            wtile[(nh*G_ + g)*FN_ + m] = f2bf(w);
        }
        __syncthreads();
        {
            const size_t base4 = ((size_t)((b*C_ + cl)*FN_ + n0 + s*2)) * 256;  // float4 units
            const float4* srcv = (const float4*)wtile;
            float4* dstv = (float4*)lw;
            dstv[base4 + t]       = srcv[t];
            dstv[base4 + t + 256] = srcv[t + 256];
        }
        __syncthreads();
    }
}

// ============ MFMA attention per (batch, class, group) ============
#define FT_OFF   0        // ft bf16 [128n][128d] swz   32 KB  (aliased by P later)
#define QL_OFF   32768    // q bf16 [128n][64dq] swz    16 KB
#define KL_OFF   49152    // k bf16 [128m][64dq] swz    16 KB
#define WT_OFF   65536    // W^T bf16 [144r][128d] swz  36 KB (aliased by affL)
#define AFF_OFF  65536    // aff f32 [128][133]         68.1 KB
#define VT_OFF   133632   // V'^T bf16 [16e][128m] swz  4 KB
#define BIAS_OFF 137728   // 128 f32
#define SMEM_SZ  138240

#define ADDR256(row, gr)  ((row)*256 + ((((gr) ^ ((row)&15))) << 4))
#define ADDR128(row, gr)  ((row)*128 + ((((gr) ^ ((row)&7))) << 4))

__global__ __launch_bounds__(1024) void k_attn(const float* __restrict__ emb_feat,
                                               const float* __restrict__ q_w, const float* __restrict__ q_b,
                                               const float* __restrict__ k_w, const float* __restrict__ k_b,
                                               const float* __restrict__ out_w, const float* __restrict__ out_b,
                                               const unsigned short* __restrict__ lw,
                                               float* __restrict__ att)
{
    const int g    = blockIdx.x & 15;
    const int rest = blockIdx.x >> 4;
    const int cl   = rest % C_;
    const int b    = rest / C_;
    const int c    = cl;
    const int t  = threadIdx.x;
    const int wave = t >> 6;
    const int lane = t & 63;
    const int lr = lane & 15;
    const int lh = lane >> 4;              // 0..3

    __shared__ char smem[SMEM_SZ];
    float* biasL = (float*)(smem + BIAS_OFF);
    float* affF  = (float*)(smem + AFF_OFF);

    // ================= P0: staging =================
    for (int s = 0; s < 4; ++s) {
        int fi = t + s*1024;
        int n  = fi >> 5;
        int d4 = (fi & 31) << 2;
        float4 v = *(const float4*)(emb_feat + ((size_t)(b*FN_ + n)*C_ + c)*FC_ + d4);
        char* dst = smem + FT_OFF + ADDR256(n, d4 >> 3) + ((d4 >> 2) & 1)*8;
        *(uint2*)dst = make_uint2((unsigned)f2bf(v.x) | ((unsigned)f2bf(v.y) << 16),
                                  (unsigned)f2bf(v.z) | ((unsigned)f2bf(v.w) << 16));
    }
    for (int s = 0; s < 2; ++s) {
        int id = t + s*1024;
        int r  = id & 127;
        int g8 = id >> 7;                  // 0..15
        const float* src = (r < 64) ? (q_w + (size_t)(g8*8)*1024 + g*DQ_ + r)
                                    : (k_w + (size_t)(g8*8)*1024 + g*DQ_ + (r-64));
        unsigned short u[8];
        #pragma unroll
        for (int j = 0; j < 8; ++j) u[j] = f2bf(src[(size_t)j*1024]);
        char* dst = smem + WT_OFF + ADDR256(r, g8);
        *(uint4*)dst = make_uint4((unsigned)u[0] | ((unsigned)u[1] << 16),
                                  (unsigned)u[2] | ((unsigned)u[3] << 16),
                                  (unsigned)u[4] | ((unsigned)u[5] << 16),
                                  (unsigned)u[6] | ((unsigned)u[7] << 16));
    }
    if (t < 128) {
        int e  = t & 7;
        int g8 = t >> 3;
        const float* src = out_w + (size_t)g*FC_*EO_ + (size_t)(g8*8)*EO_ + e;
        unsigned short u[8];
        #pragma unroll
        for (int j = 0; j < 8; ++j) u[j] = f2bf(src[(size_t)j*EO_]);
        int r = 128 + e;
        char* dst = smem + WT_OFF + ADDR256(r, g8);
        *(uint4*)dst = make_uint4((unsigned)u[0] | ((unsigned)u[1] << 16),
                                  (unsigned)u[2] | ((unsigned)u[3] << 16),
                                  (unsigned)u[4] | ((unsigned)u[5] << 16),
                                  (unsigned)u[6] | ((unsigned)u[7] << 16));
    }
    if (t >= 256 && t < 512) {
        int i = t - 256;
        *(uint2*)(smem + WT_OFF + 136*256 + i*8) = make_uint2(0u, 0u);
    }
    if (t >= 512 && t < 768) {
        int i = t - 512;
        *(uint2*)(smem + VT_OFF + 8*256 + i*8) = make_uint2(0u, 0u);
    }
    if (t >= 128 && t < 256) {
        int r = t - 128;
        biasL[r] = (r < 64) ? q_b[g*DQ_ + r] : k_b[g*DQ_ + (r-64)];
    }
    __syncthreads();

    // ================= P1: proj MFMA =================
    {
        const int rb = (wave >> 2) * 32;
        const int nb = (wave & 3) * 32;
        f32x4 acc00 = {0,0,0,0}, acc01 = {0,0,0,0}, acc10 = {0,0,0,0}, acc11 = {0,0,0,0};
        f32x4 accV  = {0,0,0,0};
        #pragma unroll
        for (int ks = 0; ks < 4; ++ks) {
            int soff = ((ks*4 + lh) ^ lr) << 4;
            bf16x8 a0 = *(const bf16x8*)(smem + WT_OFF + (rb + lr)*256 + soff);
            bf16x8 a1 = *(const bf16x8*)(smem + WT_OFF + (rb + 16 + lr)*256 + soff);
            bf16x8 b0 = *(const bf16x8*)(smem + FT_OFF + (nb + lr)*256 + soff);
            bf16x8 b1 = *(const bf16x8*)(smem + FT_OFF + (nb + 16 + lr)*256 + soff);
            acc00 = __builtin_amdgcn_mfma_f32_16x16x32_bf16(a0, b0, acc00, 0, 0, 0);
            acc01 = __builtin_amdgcn_mfma_f32_16x16x32_bf16(a0, b1, acc01, 0, 0, 0);
            acc10 = __builtin_amdgcn_mfma_f32_16x16x32_bf16(a1, b0, acc10, 0, 0, 0);
            acc11 = __builtin_amdgcn_mfma_f32_16x16x32_bf16(a1, b1, acc11, 0, 0, 0);
            if (wave < 8) {
                bf16x8 av = *(const bf16x8*)(smem + WT_OFF + (128 + lr)*256 + soff);
                bf16x8 bv = *(const bf16x8*)(smem + FT_OFF + (wave*16 + lr)*256 + soff);
                accV = __builtin_amdgcn_mfma_f32_16x16x32_bf16(av, bv, accV, 0, 0, 0);
            }
        }
        #pragma unroll
        for (int ti = 0; ti < 2; ++ti) {
            #pragma unroll
            for (int tj = 0; tj < 2; ++tj) {
                f32x4 a = (ti == 0) ? (tj == 0 ? acc00 : acc01) : (tj == 0 ? acc10 : acc11);
                int r0 = rb + ti*16 + lh*4;
                int n  = nb + tj*16 + lr;
                float v0 = a[0] + biasL[r0+0];
                float v1 = a[1] + biasL[r0+1];
                float v2 = a[2] + biasL[r0+2];
                float v3 = a[3] + biasL[r0+3];
                int dq0 = r0 & 63;
                int off = (r0 < 64 ? QL_OFF : KL_OFF);
                char* dst = smem + off + ADDR128(n, dq0 >> 3) + ((dq0 >> 2) & 1)*8;
                *(uint2*)dst = make_uint2((unsigned)f2bf(v0) | ((unsigned)f2bf(v1) << 16),
                                          (unsigned)f2bf(v2) | ((unsigned)f2bf(v3) << 16));
            }
        }
        if (wave < 8 && lh < 2) {
            int m = wave*16 + lr;
            #pragma unroll
            for (int reg = 0; reg < 4; ++reg) {
                int e = lh*4 + reg;
                char* dst = smem + VT_OFF + (e)*256 + ((((m >> 3) ^ e)) << 4) + (m & 7)*2;
                *(unsigned short*)dst = f2bf(accV[reg]);
            }
        }
    }
    __syncthreads();

    // ================= P2: aff MFMA =================
    {
        const int nb = (wave >> 2) * 32;
        const int mb = (wave & 3) * 32;
        f32x4 acc00 = {0,0,0,0}, acc01 = {0,0,0,0}, acc10 = {0,0,0,0}, acc11 = {0,0,0,0};
        #pragma unroll
        for (int ks = 0; ks < 2; ++ks) {
            int soff = ((ks*4 + lh) ^ (lr & 7)) << 4;
            bf16x8 a0 = *(const bf16x8*)(smem + QL_OFF + (nb + lr)*128 + soff);
            bf16x8 a1 = *(const bf16x8*)(smem + QL_OFF + (nb + 16 + lr)*128 + soff);
            bf16x8 b0 = *(const bf16x8*)(smem + KL_OFF + (mb + lr)*128 + soff);
            bf16x8 b1 = *(const bf16x8*)(smem + KL_OFF + (mb + 16 + lr)*128 + soff);
            acc00 = __builtin_amdgcn_mfma_f32_16x16x32_bf16(a0, b0, acc00, 0, 0, 0);
            acc01 = __builtin_amdgcn_mfma_f32_16x16x32_bf16(a0, b1, acc01, 0, 0, 0);
            acc10 = __builtin_amdgcn_mfma_f32_16x16x32_bf16(a1, b0, acc10, 0, 0, 0);
            acc11 = __builtin_amdgcn_mfma_f32_16x16x32_bf16(a1, b1, acc11, 0, 0, 0);
        }
        #pragma unroll
        for (int ti = 0; ti < 2; ++ti) {
            #pragma unroll
            for (int tj = 0; tj < 2; ++tj) {
                f32x4 a = (ti == 0) ? (tj == 0 ? acc00 : acc01) : (tj == 0 ? acc10 : acc11);
                int n0 = nb + ti*16 + lh*4;
                int m  = mb + tj*16 + lr;
                #pragma unroll
                for (int reg = 0; reg < 4; ++reg)
                    affF[(n0 + reg)*133 + m] = a[reg];
            }
        }
    }
    __syncthreads();

    // ================= P3: softmax + P bf16 over ft =================
    {
        const int row = t >> 3;
        const int lp  = t & 7;
        const int m0  = lp * 16;
        const unsigned short* lwrow = lw + ((((size_t)(b*C_ + cl))*FN_ + row)*G_ + g)*FN_ + m0;
        float v[16];
        float mx = -INFINITY;
        #pragma unroll
        for (int j = 0; j < 16; ++j) {
            float val = affF[row*133 + m0 + j]*0.125f + __logf(bf2f(lwrow[j]));
            v[j] = val;
            mx = fmaxf(mx, val);
        }
        #pragma unroll
        for (int s = 1; s < 8; s <<= 1) mx = fmaxf(mx, __shfl_xor(mx, s, 8));
        float sum = 0.f;
        #pragma unroll
        for (int j = 0; j < 16; ++j) { v[j] = __expf(v[j] - mx); sum += v[j]; }
        #pragma unroll
        for (int s = 1; s < 8; s <<= 1) sum += __shfl_xor(sum, s, 8);
        float rs = 1.0f / sum;
        unsigned short u[16];
        #pragma unroll
        for (int j = 0; j < 16; ++j) u[j] = f2bf(v[j] * rs);
        char* d0 = smem + FT_OFF + ADDR256(row, lp*2);
        char* d1 = smem + FT_OFF + ADDR256(row, lp*2 + 1);
        *(uint4*)d0 = make_uint4((unsigned)u[0] | ((unsigned)u[1] << 16),
                                 (unsigned)u[2] | ((unsigned)u[3] << 16),
                                 (unsigned)u[4] | ((unsigned)u[5] << 16),
                                 (unsigned)u[6] | ((unsigned)u[7] << 16));
        *(uint4*)d1 = make_uint4((unsigned)u[8]  | ((unsigned)u[9]  << 16),
                                 (unsigned)u[10] | ((unsigned)u[11] << 16),
                                 (unsigned)u[12] | ((unsigned)u[13] << 16),
                                 (unsigned)u[14] | ((unsigned)u[15] << 16));
    }
    __syncthreads();

    // ================= P4: att = P @ V' =================
    if (wave < 8) {
        const int tb = wave * 16;
        f32x4 acc = {0,0,0,0};
        #pragma unroll
        for (int ks = 0; ks < 4; ++ks) {
            int soff = ((ks*4 + lh) ^ lr) << 4;
            bf16x8 a = *(const bf16x8*)(smem + FT_OFF + (tb + lr)*256 + soff);
            bf16x8 bv = *(const bf16x8*)(smem + VT_OFF + lr*256 + soff);
            acc = __builtin_amdgcn_mfma_f32_16x16x32_bf16(a, bv, acc, 0, 0, 0);
        }
        if (lr < 8) {
            float ob = out_b[g*EO_ + lr];
            #pragma unroll
            for (int reg = 0; reg < 4; ++reg) {
                int n = tb + lh*4 + reg;
                att[((size_t)(b*FN_ + n)*C_ + c)*FC_ + g*EO_ + lr] = acc[reg] + ob;
            }
        }
    }
}

// ============ final: 8 items/block, 32 lanes/item ============
__global__ __launch_bounds__(256) void k_final(const float* __restrict__ emb_feat,
                                               const float* __restrict__ att,
                                               const float* __restrict__ logit_w,
                                               const float* __restrict__ logit_b,
                                               const float* __restrict__ sorted_score,
                                               float* __restrict__ out)
{
    __shared__ float lwL[FC_*NT_ + NT_];
    const int t = threadIdx.x;
    for (int i = t; i < FC_*NT_ + NT_; i += 256)
        lwL[i] = (i < FC_*NT_) ? logit_w[i] : logit_b[i - FC_*NT_];
    __syncthreads();
    const int item = blockIdx.x*8 + (t >> 5);
    const int l = t & 31;
    const int d0 = l*4;
    float4 ev = *(const float4*)(emb_feat + (size_t)item*FC_ + d0);
    float4 av = *(const float4*)(att + (size_t)item*FC_ + d0);
    float a0 = fmaxf(ev.x + av.x, 0.f);
    float a1 = fmaxf(ev.y + av.y, 0.f);
    float a2 = fmaxf(ev.z + av.z, 0.f);
    float a3 = fmaxf(ev.w + av.w, 0.f);
    float s0 = a0*lwL[(d0+0)*NT_+0] + a1*lwL[(d0+1)*NT_+0] + a2*lwL[(d0+2)*NT_+0] + a3*lwL[(d0+3)*NT_+0];
    float s1 = a0*lwL[(d0+0)*NT_+1] + a1*lwL[(d0+1)*NT_+1] + a2*lwL[(d0+2)*NT_+1] + a3*lwL[(d0+3)*NT_+1];
    float s2 = a0*lwL[(d0+0)*NT_+2] + a1*lwL[(d0+1)*NT_+2] + a2*lwL[(d0+2)*NT_+2] + a3*lwL[(d0+3)*NT_+2];
    #pragma unroll
    for (int s = 1; s < 32; s <<= 1) {
        s0 += __shfl_xor(s0, s, 32);
        s1 += __shfl_xor(s1, s, 32);
        s2 += __shfl_xor(s2, s, 32);
    }
    if (l < NT_) {
        float lg = (l == 0) ? s0 : (l == 1) ? s1 : s2;
        lg += lwL[FC_*NT_ + l];
        float sg = 1.f / (1.f + expf(-lg));
        out[(size_t)item*NT_ + l] = sg * sorted_score[item];
    }
}

extern "C" void kernel_launch(void* const* d_in, const int* in_sizes, int n_in,
                              void* d_out, int out_size, void* d_ws, size_t ws_size,
                              hipStream_t stream) {
    (void)in_sizes; (void)n_in; (void)out_size; (void)ws_size;
    const float* roi_feat = (const float*)d_in[0];
    const float* scores   = (const float*)d_in[1];
    const float* pdeltas  = (const float*)d_in[2];
    const float* pboxes   = (const float*)d_in[3];
    const float* roi_w    = (const float*)d_in[4];
    const float* roi_b    = (const float*)d_in[5];
    const float* rank_w   = (const float*)d_in[6];
    const float* rank_b   = (const float*)d_in[7];
    const float* logit_w  = (const float*)d_in[8];
    const float* logit_b  = (const float*)d_in[9];
    const float* pos_w    = (const float*)d_in[10];
    const float* pos_b    = (const float*)d_in[11];
    const float* q_w      = (const float*)d_in[12];
    const float* q_b      = (const float*)d_in[13];
    const float* k_w      = (const float*)d_in[14];
    const float* k_b      = (const float*)d_in[15];
    const float* out_w    = (const float*)d_in[16];
    const float* out_b    = (const float*)d_in[17];
    float* ws = (float*)d_ws;

    float* roiP         = ws + O_ROIP;
    float* rankP        = ws + O_RANKP;
    int*   rank_idx     = (int*)(ws + O_RANKIDX);
    float* sorted_score = ws + O_SSCORE;
    float* sorted_boxes = ws + O_SBOX;
    float* emb_feat     = ws + O_EMB;
    float* att          = ws + O_ATT;
    unsigned short* lwb = (unsigned short*)(ws + O_LW);

    k_embed<<<dim3(144), dim3(256), 0, stream>>>(roi_feat, roi_w, roi_b, rank_w, rank_b,
                                                 roiP, rankP);
    k_topk<<<dim3(B_*C_), dim3(512), 0, stream>>>(scores, rank_idx, sorted_score);
    k_gather<<<dim3(B_*FN_*C_/8), dim3(256), 0, stream>>>(rank_idx, roiP, rankP,
                                                          pdeltas, pboxes, emb_feat, sorted_boxes);
    k_pos2<<<dim3(B_*C_*32), dim3(256), 0, stream>>>(sorted_boxes, pos_w, pos_b, lwb);
    k_attn<<<dim3(B_*C_*G_), dim3(1024), 0, stream>>>(emb_feat, q_w, q_b, k_w, k_b,
                                                      out_w, out_b, lwb, att);
    k_final<<<dim3(B_*FN_*C_/8), dim3(256), 0, stream>>>(emb_feat, att, logit_w, logit_b,
                                                         sorted_score, d_out ? (float*)d_out : nullptr);
}

// Round 8
// 180.316 us; speedup vs baseline: 2.3391x; 1.3917x over previous
//
#include <hip/hip_runtime.h>
#include <math.h>

#define B_    2
#define NB_   512
#define C_    80
#define FEAT_ 1024
#define FN_   128
#define FC_   128
#define PE_   64
#define G_    16
#define DQ_   64
#define EO_   8
#define NT_   3
#define SCALE_CLAMP_ 4.135166556742356f

typedef __attribute__((ext_vector_type(8))) short bf16x8;
typedef __attribute__((ext_vector_type(4))) float f32x4;

// ---- workspace layout (float offsets) ----
#define O_ROIP    ((size_t)0)                                   // 2*1024*128 (K-half partials)
#define O_RANKP   (O_ROIP + (size_t)2*B_*NB_*FC_)               // 2*128*128
#define O_RANKIDX (O_RANKP + (size_t)2*FN_*FC_)                 // B*128*80 (int)
#define O_SSCORE  (O_RANKIDX + (size_t)B_*FN_*C_)               // B*128*80
#define O_SBOX    (O_SSCORE + (size_t)B_*FN_*C_)                // B*128*80*4
#define O_EMB     (O_SBOX + (size_t)B_*FN_*C_*4)                // B*128*80*128
#define O_ATT     (O_EMB + (size_t)B_*FN_*C_*FC_)               // B*128*80*128
#define O_LW      (O_ATT + (size_t)B_*FN_*C_*FC_)               // 2*80*128*16*128 ushort = 84MB

__device__ __forceinline__ float bf2f(unsigned short u) {
    return __uint_as_float(((unsigned int)u) << 16);
}
__device__ __forceinline__ unsigned short f2bf(float f) {
    unsigned int x = __float_as_uint(f);
    unsigned int r = (x + 0x7fff + ((x >> 16) & 1)) >> 16;   // RNE
    return (unsigned short)r;
}

// 16B-granule swizzle, 128B row (8 granules)
#define ADDR128(row, gr)  ((row)*128 + ((((gr) ^ ((row)&7))) << 4))
// 16B-granule swizzle, 256B row (16 granules)
#define ADDR256(row, gr)  ((row)*256 + ((((gr) ^ ((row)&15))) << 4))

// ============ embed GEMMs: roi (row-tiles 0..63) + rank (64..71), x2 K-halves ============
__global__ __launch_bounds__(256) void k_embed(const float* __restrict__ roi_feat,
                                               const float* __restrict__ roi_w,
                                               const float* __restrict__ roi_b,
                                               const float* __restrict__ rank_w,
                                               const float* __restrict__ rank_b,
                                               float* __restrict__ roiP,
                                               float* __restrict__ rankP)
{
    const int bid = blockIdx.x;
    const int kh  = bid & 1;
    const int rt  = bid >> 1;            // 0..71
    const bool isRank = rt >= 64;
    const int row0 = (isRank ? rt - 64 : rt) * 16;
    const int t = threadIdx.x;
    const int w = t >> 6, lane = t & 63, lr = lane & 15, lh = lane >> 4;
    const int col0 = w * 32;
    const float* W = isRank ? rank_w : roi_w;
    const float* bias = isRank ? rank_b : roi_b;

    const int arow = row0 + lr;
    f32x4 acc0 = {0,0,0,0}, acc1 = {0,0,0,0};

    #pragma unroll 4
    for (int ks = 0; ks < 16; ++ks) {
        const int kb = kh*512 + ks*32 + lh*8;
        bf16x8 af;
        if (!isRank) {
            float4 a0 = *(const float4*)(roi_feat + (size_t)arow*FEAT_ + kb);
            float4 a1 = *(const float4*)(roi_feat + (size_t)arow*FEAT_ + kb + 4);
            af[0] = (short)f2bf(a0.x); af[1] = (short)f2bf(a0.y);
            af[2] = (short)f2bf(a0.z); af[3] = (short)f2bf(a0.w);
            af[4] = (short)f2bf(a1.x); af[5] = (short)f2bf(a1.y);
            af[6] = (short)f2bf(a1.z); af[7] = (short)f2bf(a1.w);
        } else {
            #pragma unroll
            for (int j = 0; j < 8; ++j) {
                int k = kb + j;
                int kk = k & 511;
                float inv = exp2f(-(float)kk * 0.0194644226f);  // log2(1000)/512
                float arg = (float)arow * inv;
                float v = (k < 512) ? __sinf(arg) : __cosf(arg);
                af[j] = (short)f2bf(v);
            }
        }
        bf16x8 bf0, bf1;
        #pragma unroll
        for (int j = 0; j < 8; ++j) {
            const float* wr = W + (size_t)(kb + j)*FC_ + col0 + lr;
            bf0[j] = (short)f2bf(wr[0]);
            bf1[j] = (short)f2bf(wr[16]);
        }
        acc0 = __builtin_amdgcn_mfma_f32_16x16x32_bf16(af, bf0, acc0, 0, 0, 0);
        acc1 = __builtin_amdgcn_mfma_f32_16x16x32_bf16(af, bf1, acc1, 0, 0, 0);
    }
    float* dst = isRank ? (rankP + (size_t)kh*FN_*FC_) : (roiP + (size_t)kh*(B_*NB_)*FC_);
    #pragma unroll
    for (int tile = 0; tile < 2; ++tile) {
        f32x4 a = tile ? acc1 : acc0;
        int col = col0 + tile*16 + lr;
        float bv = (kh == 0) ? bias[col] : 0.0f;
        #pragma unroll
        for (int reg = 0; reg < 4; ++reg) {
            int rr = row0 + lh*4 + reg;
            dst[(size_t)rr*FC_ + col] = a[reg] + bv;
        }
    }
}

// ============ softmax over boxes + stable top-128 rank ============
__global__ __launch_bounds__(512) void k_topk(const float* __restrict__ scores,
                                              int* __restrict__ rank_idx,
                                              float* __restrict__ sorted_score)
{
    int b = blockIdx.x / C_, c = blockIdx.x % C_;
    __shared__ float p[NB_];
    __shared__ float red[NB_];
    int i = threadIdx.x;
    float s = scores[(size_t)(b*NB_ + i)*(C_+1) + c];
    red[i] = s; __syncthreads();
    for (int o = 256; o > 0; o >>= 1) { if (i < o) red[i] = fmaxf(red[i], red[i+o]); __syncthreads(); }
    float mx = red[0]; __syncthreads();
    float e = expf(s - mx);
    red[i] = e; __syncthreads();
    for (int o = 256; o > 0; o >>= 1) { if (i < o) red[i] += red[i+o]; __syncthreads(); }
    float sum = red[0]; __syncthreads();
    float pi = e / sum;
    p[i] = pi; __syncthreads();
    int rank = 0;
    for (int j = 0; j < NB_; ++j) {
        float pj = p[j];
        rank += (pj > pi) || (pj == pi && j < i);
    }
    if (rank < FN_) {
        rank_idx[(size_t)(b*FN_ + rank)*C_ + c] = i;
        sorted_score[(size_t)(b*FN_ + rank)*C_ + c] = pi;
    }
}

// ============ gather emb_feat (sum K-half partials) + refined boxes ============
__global__ __launch_bounds__(256) void k_gather(const int* __restrict__ rank_idx,
                                                const float* __restrict__ roiP,
                                                const float* __restrict__ rankP,
                                                const float* __restrict__ pdeltas,
                                                const float* __restrict__ pboxes,
                                                float* __restrict__ emb_feat,
                                                float* __restrict__ sorted_boxes)
{
    const int t = threadIdx.x;
    const int item = blockIdx.x*8 + (t >> 5);
    const int l = t & 31;
    const int c = item % C_;
    const int bn = item / C_;
    const int n = bn & (FN_-1);
    const int b = bn >> 7;
    const int idx = rank_idx[item];
    const int row = b*NB_ + idx;
    float4 e0 = *(const float4*)(roiP + (size_t)row*FC_ + l*4);
    float4 e1 = *(const float4*)(roiP + (size_t)(B_*NB_ + row)*FC_ + l*4);
    float4 r0 = *(const float4*)(rankP + (size_t)n*FC_ + l*4);
    float4 r1 = *(const float4*)(rankP + (size_t)(FN_ + n)*FC_ + l*4);
    *(float4*)(emb_feat + (size_t)item*FC_ + l*4) =
        make_float4(e0.x+e1.x+r0.x+r1.x, e0.y+e1.y+r0.y+r1.y,
                    e0.z+e1.z+r0.z+r1.z, e0.w+e1.w+r0.w+r1.w);
    if (l == 0) {
        float x1 = pboxes[row*4+0], y1 = pboxes[row*4+1], x2 = pboxes[row*4+2], y2 = pboxes[row*4+3];
        float w = x2 - x1, h = y2 - y1;
        float cx = x1 + 0.5f*w, cy = y1 + 0.5f*h;
        const float* dl = pdeltas + (size_t)row*(C_*4) + c*4;
        float dx = dl[0]/10.0f, dy = dl[1]/10.0f;
        float dw = fminf(dl[2]/5.0f, SCALE_CLAMP_);
        float dh = fminf(dl[3]/5.0f, SCALE_CLAMP_);
        float pcx = dx*w + cx, pcy = dy*h + cy;
        float pw = expf(dw)*w, ph = expf(dh)*h;
        float* ob = sorted_boxes + (size_t)item*4;
        ob[0] = pcx - 0.5f*pw; ob[1] = pcy - 0.5f*ph;
        ob[2] = pcx + 0.5f*pw; ob[3] = pcy + 0.5f*ph;
    }
}

// ============ prior w via MFMA: features bf16 -> e @ pos_w ============
// grid: B*C*64 (2 n per block, 256 pairs), 256 threads.
// lw layout: [b*C+cl][n][g][m] bf16 (pre-log, relu+1e-6 clamped)
__global__ __launch_bounds__(256) void k_pos2(const float* __restrict__ sorted_boxes,
                                              const float* __restrict__ pos_w,
                                              const float* __restrict__ pos_b,
                                              unsigned short* __restrict__ lw)
{
    const int n2   = blockIdx.x & 63;
    const int rest = blockIdx.x >> 6;
    const int cl   = rest % C_;
    const int b    = rest / C_;
    const int n0   = n2 * 2;
    const int t    = threadIdx.x;

    __shared__ float geomL[FN_][6];               // 3 KB
    __shared__ unsigned short featL[256*PE_];     // 32 KB, swizzled 128B rows
    __shared__ unsigned short poswL[G_*PE_];      // 2 KB, swizzled 128B rows
    __shared__ float pbL[G_];
    __shared__ float sdimL[8];

    // ---- staging
    if (t < FN_) {
        const float* bx = sorted_boxes + (((size_t)(b*FN_ + t))*C_ + cl)*4;
        float x1 = bx[0], y1 = bx[1], x2 = bx[2], y2 = bx[3];
        float w = x2 - x1 + 1.0f;
        float h = y2 - y1 + 1.0f;
        geomL[t][0] = 0.5f*(x1+x2);
        geomL[t][1] = 0.5f*(y1+y2);
        geomL[t][2] = w;
        geomL[t][3] = h;
        geomL[t][4] = __logf(w);
        geomL[t][5] = __logf(h);
    } else {
        // pos_w^T: id 0..127 -> g = id>>3, gr = id&7, pe = gr*8 + j
        int id = t - 128;
        int g  = id >> 3;
        int gr = id & 7;
        unsigned short u[8];
        #pragma unroll
        for (int j = 0; j < 8; ++j) u[j] = f2bf(pos_w[(gr*8 + j)*G_ + g]);
        *(uint4*)((char*)poswL + ADDR128(g, gr)) =
            make_uint4((unsigned)u[0] | ((unsigned)u[1] << 16),
                       (unsigned)u[2] | ((unsigned)u[3] << 16),
                       (unsigned)u[4] | ((unsigned)u[5] << 16),
                       (unsigned)u[6] | ((unsigned)u[7] << 16));
    }
    if (t < G_) pbL[t] = pos_b[t];
    if (t >= 16 && t < 24) sdimL[t-16] = 1.0f / powf(1000.0f, 0.125f*(float)(t-16));
    __syncthreads();

    // ---- features: thread t = pair (n_local = t>>7, m = t&127)
    {
        const int nl = t >> 7;
        const int m  = t & 127;
        const int n  = n0 + nl;
        float pm[4];
        {
            float cxn = geomL[n][0], cyn = geomL[n][1];
            float rwn = 1.0f/geomL[n][2], rhn = 1.0f/geomL[n][3];
            pm[0] = __logf(fmaxf(fabsf((cxn - geomL[m][0]) * rwn), 1e-3f)) * 100.0f;
            pm[1] = __logf(fmaxf(fabsf((cyn - geomL[m][1]) * rhn), 1e-3f)) * 100.0f;
            pm[2] = (geomL[n][4] - geomL[m][4]) * 100.0f;
            pm[3] = (geomL[n][5] - geomL[m][5]) * 100.0f;
        }
        char* base = (char*)featL;
        #pragma unroll
        for (int f = 0; f < 4; ++f) {
            float s[8], c[8];
            #pragma unroll
            for (int r = 0; r < 8; ++r) {
                __sincosf(pm[f] * sdimL[r], &s[r], &c[r]);
            }
            unsigned short us[8], uc[8];
            #pragma unroll
            for (int r = 0; r < 8; ++r) { us[r] = f2bf(s[r]); uc[r] = f2bf(c[r]); }
            *(uint4*)(base + ADDR128(t, 2*f)) =
                make_uint4((unsigned)us[0] | ((unsigned)us[1] << 16),
                           (unsigned)us[2] | ((unsigned)us[3] << 16),
                           (unsigned)us[4] | ((unsigned)us[5] << 16),
                           (unsigned)us[6] | ((unsigned)us[7] << 16));
            *(uint4*)(base + ADDR128(t, 2*f + 1)) =
                make_uint4((unsigned)uc[0] | ((unsigned)uc[1] << 16),
                           (unsigned)uc[2] | ((unsigned)uc[3] << 16),
                           (unsigned)uc[4] | ((unsigned)uc[5] << 16),
                           (unsigned)uc[6] | ((unsigned)uc[7] << 16));
        }
    }
    __syncthreads();

    // ---- MFMA: 16 tiles of 16 pairs x 16 g, K=64
    {
        const int wave = t >> 6, lane = t & 63;
        const int lr = lane & 15, lh = lane >> 4;
        const float pbg = pbL[lr];           // g = lr
        #pragma unroll
        for (int ti = 0; ti < 4; ++ti) {
            const int t16 = wave*4 + ti;
            f32x4 acc = {0,0,0,0};
            #pragma unroll
            for (int ks = 0; ks < 2; ++ks) {
                bf16x8 a  = *(const bf16x8*)((char*)featL + ADDR128(t16*16 + lr, ks*4 + lh));
                bf16x8 bb = *(const bf16x8*)((char*)poswL + ADDR128(lr, ks*4 + lh));
                acc = __builtin_amdgcn_mfma_f32_16x16x32_bf16(a, bb, acc, 0, 0, 0);
            }
            const int g = lr;
            #pragma unroll
            for (int reg = 0; reg < 4; ++reg) {
                int p = t16*16 + lh*4 + reg;
                int n = n0 + (p >> 7);
                int m = p & 127;
                float w = fmaxf(fmaxf(acc[reg] + pbg, 0.0f), 1e-6f);
                lw[(((size_t)(b*C_ + cl)*FN_ + n)*G_ + g)*FN_ + m] = f2bf(w);
            }
        }
    }
}

// ============ MFMA attention per (batch, class, group) ============
#define FT_OFF   0        // ft bf16 [128n][128d] swz   32 KB  (aliased by P later)
#define QL_OFF   32768    // q bf16 [128n][64dq] swz    16 KB
#define KL_OFF   49152    // k bf16 [128m][64dq] swz    16 KB
#define WT_OFF   65536    // W^T bf16 [144r][128d] swz  36 KB (aliased by affL)
#define AFF_OFF  65536    // aff f32 [128][133]         68.1 KB
#define VT_OFF   133632   // V'^T bf16 [16e][128m] swz  4 KB
#define BIAS_OFF 137728   // 128 f32
#define SMEM_SZ  138240

__global__ __launch_bounds__(1024) void k_attn(const float* __restrict__ emb_feat,
                                               const float* __restrict__ q_w, const float* __restrict__ q_b,
                                               const float* __restrict__ k_w, const float* __restrict__ k_b,
                                               const float* __restrict__ out_w, const float* __restrict__ out_b,
                                               const unsigned short* __restrict__ lw,
                                               float* __restrict__ att)
{
    const int g    = blockIdx.x & 15;
    const int rest = blockIdx.x >> 4;
    const int cl   = rest % C_;
    const int b    = rest / C_;
    const int c    = cl;
    const int t  = threadIdx.x;
    const int wave = t >> 6;
    const int lane = t & 63;
    const int lr = lane & 15;
    const int lh = lane >> 4;              // 0..3

    __shared__ char smem[SMEM_SZ];
    float* biasL = (float*)(smem + BIAS_OFF);
    float* affF  = (float*)(smem + AFF_OFF);

    // ================= P0: staging =================
    for (int s = 0; s < 4; ++s) {
        int fi = t + s*1024;
        int n  = fi >> 5;
        int d4 = (fi & 31) << 2;
        float4 v = *(const float4*)(emb_feat + ((size_t)(b*FN_ + n)*C_ + c)*FC_ + d4);
        char* dst = smem + FT_OFF + ADDR256(n, d4 >> 3) + ((d4 >> 2) & 1)*8;
        *(uint2*)dst = make_uint2((unsigned)f2bf(v.x) | ((unsigned)f2bf(v.y) << 16),
                                  (unsigned)f2bf(v.z) | ((unsigned)f2bf(v.w) << 16));
    }
    for (int s = 0; s < 2; ++s) {
        int id = t + s*1024;
        int r  = id & 127;
        int g8 = id >> 7;                  // 0..15
        const float* src = (r < 64) ? (q_w + (size_t)(g8*8)*1024 + g*DQ_ + r)
                                    : (k_w + (size_t)(g8*8)*1024 + g*DQ_ + (r-64));
        unsigned short u[8];
        #pragma unroll
        for (int j = 0; j < 8; ++j) u[j] = f2bf(src[(size_t)j*1024]);
        char* dst = smem + WT_OFF + ADDR256(r, g8);
        *(uint4*)dst = make_uint4((unsigned)u[0] | ((unsigned)u[1] << 16),
                                  (unsigned)u[2] | ((unsigned)u[3] << 16),
                                  (unsigned)u[4] | ((unsigned)u[5] << 16),
                                  (unsigned)u[6] | ((unsigned)u[7] << 16));
    }
    if (t < 128) {
        int e  = t & 7;
        int g8 = t >> 3;
        const float* src = out_w + (size_t)g*FC_*EO_ + (size_t)(g8*8)*EO_ + e;
        unsigned short u[8];
        #pragma unroll
        for (int j = 0; j < 8; ++j) u[j] = f2bf(src[(size_t)j*EO_]);
        int r = 128 + e;
        char* dst = smem + WT_OFF + ADDR256(r, g8);
        *(uint4*)dst = make_uint4((unsigned)u[0] | ((unsigned)u[1] << 16),
                                  (unsigned)u[2] | ((unsigned)u[3] << 16),
                                  (unsigned)u[4] | ((unsigned)u[5] << 16),
                                  (unsigned)u[6] | ((unsigned)u[7] << 16));
    }
    if (t >= 256 && t < 512) {
        int i = t - 256;
        *(uint2*)(smem + WT_OFF + 136*256 + i*8) = make_uint2(0u, 0u);
    }
    if (t >= 512 && t < 768) {
        int i = t - 512;
        *(uint2*)(smem + VT_OFF + 8*256 + i*8) = make_uint2(0u, 0u);
    }
    if (t >= 128 && t < 256) {
        int r = t - 128;
        biasL[r] = (r < 64) ? q_b[g*DQ_ + r] : k_b[g*DQ_ + (r-64)];
    }
    __syncthreads();

    // ================= P1: proj MFMA =================
    {
        const int rb = (wave >> 2) * 32;
        const int nb = (wave & 3) * 32;
        f32x4 acc00 = {0,0,0,0}, acc01 = {0,0,0,0}, acc10 = {0,0,0,0}, acc11 = {0,0,0,0};
        f32x4 accV  = {0,0,0,0};
        #pragma unroll
        for (int ks = 0; ks < 4; ++ks) {
            int soff = ((ks*4 + lh) ^ lr) << 4;
            bf16x8 a0 = *(const bf16x8*)(smem + WT_OFF + (rb + lr)*256 + soff);
            bf16x8 a1 = *(const bf16x8*)(smem + WT_OFF + (rb + 16 + lr)*256 + soff);
            bf16x8 b0 = *(const bf16x8*)(smem + FT_OFF + (nb + lr)*256 + soff);
            bf16x8 b1 = *(const bf16x8*)(smem + FT_OFF + (nb + 16 + lr)*256 + soff);
            acc00 = __builtin_amdgcn_mfma_f32_16x16x32_bf16(a0, b0, acc00, 0, 0, 0);
            acc01 = __builtin_amdgcn_mfma_f32_16x16x32_bf16(a0, b1, acc01, 0, 0, 0);
            acc10 = __builtin_amdgcn_mfma_f32_16x16x32_bf16(a1, b0, acc10, 0, 0, 0);
            acc11 = __builtin_amdgcn_mfma_f32_16x16x32_bf16(a1, b1, acc11, 0, 0, 0);
            if (wave < 8) {
                bf16x8 av = *(const bf16x8*)(smem + WT_OFF + (128 + lr)*256 + soff);
                bf16x8 bv = *(const bf16x8*)(smem + FT_OFF + (wave*16 + lr)*256 + soff);
                accV = __builtin_amdgcn_mfma_f32_16x16x32_bf16(av, bv, accV, 0, 0, 0);
            }
        }
        #pragma unroll
        for (int ti = 0; ti < 2; ++ti) {
            #pragma unroll
            for (int tj = 0; tj < 2; ++tj) {
                f32x4 a = (ti == 0) ? (tj == 0 ? acc00 : acc01) : (tj == 0 ? acc10 : acc11);
                int r0 = rb + ti*16 + lh*4;
                int n  = nb + tj*16 + lr;
                float v0 = a[0] + biasL[r0+0];
                float v1 = a[1] + biasL[r0+1];
                float v2 = a[2] + biasL[r0+2];
                float v3 = a[3] + biasL[r0+3];
                int dq0 = r0 & 63;
                int off = (r0 < 64 ? QL_OFF : KL_OFF);
                char* dst = smem + off + ADDR128(n, dq0 >> 3) + ((dq0 >> 2) & 1)*8;
                *(uint2*)dst = make_uint2((unsigned)f2bf(v0) | ((unsigned)f2bf(v1) << 16),
                                          (unsigned)f2bf(v2) | ((unsigned)f2bf(v3) << 16));
            }
        }
        if (wave < 8 && lh < 2) {
            int m = wave*16 + lr;
            #pragma unroll
            for (int reg = 0; reg < 4; ++reg) {
                int e = lh*4 + reg;
                char* dst = smem + VT_OFF + (e)*256 + ((((m >> 3) ^ e)) << 4) + (m & 7)*2;
                *(unsigned short*)dst = f2bf(accV[reg]);
            }
        }
    }
    __syncthreads();

    // ================= P2: aff MFMA =================
    {
        const int nb = (wave >> 2) * 32;
        const int mb = (wave & 3) * 32;
        f32x4 acc00 = {0,0,0,0}, acc01 = {0,0,0,0}, acc10 = {0,0,0,0}, acc11 = {0,0,0,0};
        #pragma unroll
        for (int ks = 0; ks < 2; ++ks) {
            int soff = ((ks*4 + lh) ^ (lr & 7)) << 4;
            bf16x8 a0 = *(const bf16x8*)(smem + QL_OFF + (nb + lr)*128 + soff);
            bf16x8 a1 = *(const bf16x8*)(smem + QL_OFF + (nb + 16 + lr)*128 + soff);
            bf16x8 b0 = *(const bf16x8*)(smem + KL_OFF + (mb + lr)*128 + soff);
            bf16x8 b1 = *(const bf16x8*)(smem + KL_OFF + (mb + 16 + lr)*128 + soff);
            acc00 = __builtin_amdgcn_mfma_f32_16x16x32_bf16(a0, b0, acc00, 0, 0, 0);
            acc01 = __builtin_amdgcn_mfma_f32_16x16x32_bf16(a0, b1, acc01, 0, 0, 0);
            acc10 = __builtin_amdgcn_mfma_f32_16x16x32_bf16(a1, b0, acc10, 0, 0, 0);
            acc11 = __builtin_amdgcn_mfma_f32_16x16x32_bf16(a1, b1, acc11, 0, 0, 0);
        }
        #pragma unroll
        for (int ti = 0; ti < 2; ++ti) {
            #pragma unroll
            for (int tj = 0; tj < 2; ++tj) {
                f32x4 a = (ti == 0) ? (tj == 0 ? acc00 : acc01) : (tj == 0 ? acc10 : acc11);
                int n0 = nb + ti*16 + lh*4;
                int m  = mb + tj*16 + lr;
                #pragma unroll
                for (int reg = 0; reg < 4; ++reg)
                    affF[(n0 + reg)*133 + m] = a[reg];
            }
        }
    }
    __syncthreads();

    // ================= P3: softmax + P bf16 over ft =================
    {
        const int row = t >> 3;
        const int lp  = t & 7;
        const int m0  = lp * 16;
        const unsigned short* lwrow = lw + ((((size_t)(b*C_ + cl))*FN_ + row)*G_ + g)*FN_ + m0;
        float v[16];
        float mx = -INFINITY;
        #pragma unroll
        for (int j = 0; j < 16; ++j) {
            float val = affF[row*133 + m0 + j]*0.125f + __logf(bf2f(lwrow[j]));
            v[j] = val;
            mx = fmaxf(mx, val);
        }
        #pragma unroll
        for (int s = 1; s < 8; s <<= 1) mx = fmaxf(mx, __shfl_xor(mx, s, 8));
        float sum = 0.f;
        #pragma unroll
        for (int j = 0; j < 16; ++j) { v[j] = __expf(v[j] - mx); sum += v[j]; }
        #pragma unroll
        for (int s = 1; s < 8; s <<= 1) sum += __shfl_xor(sum, s, 8);
        float rs = 1.0f / sum;
        unsigned short u[16];
        #pragma unroll
        for (int j = 0; j < 16; ++j) u[j] = f2bf(v[j] * rs);
        char* d0 = smem + FT_OFF + ADDR256(row, lp*2);
        char* d1 = smem + FT_OFF + ADDR256(row, lp*2 + 1);
        *(uint4*)d0 = make_uint4((unsigned)u[0] | ((unsigned)u[1] << 16),
                                 (unsigned)u[2] | ((unsigned)u[3] << 16),
                                 (unsigned)u[4] | ((unsigned)u[5] << 16),
                                 (unsigned)u[6] | ((unsigned)u[7] << 16));
        *(uint4*)d1 = make_uint4((unsigned)u[8]  | ((unsigned)u[9]  << 16),
                                 (unsigned)u[10] | ((unsigned)u[11] << 16),
                                 (unsigned)u[12] | ((unsigned)u[13] << 16),
                                 (unsigned)u[14] | ((unsigned)u[15] << 16));
    }
    __syncthreads();

    // ================= P4: att = P @ V' =================
    if (wave < 8) {
        const int tb = wave * 16;
        f32x4 acc = {0,0,0,0};
        #pragma unroll
        for (int ks = 0; ks < 4; ++ks) {
            int soff = ((ks*4 + lh) ^ lr) << 4;
            bf16x8 a = *(const bf16x8*)(smem + FT_OFF + (tb + lr)*256 + soff);
            bf16x8 bv = *(const bf16x8*)(smem + VT_OFF + lr*256 + soff);
            acc = __builtin_amdgcn_mfma_f32_16x16x32_bf16(a, bv, acc, 0, 0, 0);
        }
        if (lr < 8) {
            float ob = out_b[g*EO_ + lr];
            #pragma unroll
            for (int reg = 0; reg < 4; ++reg) {
                int n = tb + lh*4 + reg;
                att[((size_t)(b*FN_ + n)*C_ + c)*FC_ + g*EO_ + lr] = acc[reg] + ob;
            }
        }
    }
}

// ============ final: 8 items/block, 32 lanes/item ============
__global__ __launch_bounds__(256) void k_final(const float* __restrict__ emb_feat,
                                               const float* __restrict__ att,
                                               const float* __restrict__ logit_w,
                                               const float* __restrict__ logit_b,
                                               const float* __restrict__ sorted_score,
                                               float* __restrict__ out)
{
    __shared__ float lwL[FC_*NT_ + NT_];
    const int t = threadIdx.x;
    for (int i = t; i < FC_*NT_ + NT_; i += 256)
        lwL[i] = (i < FC_*NT_) ? logit_w[i] : logit_b[i - FC_*NT_];
    __syncthreads();
    const int item = blockIdx.x*8 + (t >> 5);
    const int l = t & 31;
    const int d0 = l*4;
    float4 ev = *(const float4*)(emb_feat + (size_t)item*FC_ + d0);
    float4 av = *(const float4*)(att + (size_t)item*FC_ + d0);
    float a0 = fmaxf(ev.x + av.x, 0.f);
    float a1 = fmaxf(ev.y + av.y, 0.f);
    float a2 = fmaxf(ev.z + av.z, 0.f);
    float a3 = fmaxf(ev.w + av.w, 0.f);
    float s0 = a0*lwL[(d0+0)*NT_+0] + a1*lwL[(d0+1)*NT_+0] + a2*lwL[(d0+2)*NT_+0] + a3*lwL[(d0+3)*NT_+0];
    float s1 = a0*lwL[(d0+0)*NT_+1] + a1*lwL[(d0+1)*NT_+1] + a2*lwL[(d0+2)*NT_+1] + a3*lwL[(d0+3)*NT_+1];
    float s2 = a0*lwL[(d0+0)*NT_+2] + a1*lwL[(d0+1)*NT_+2] + a2*lwL[(d0+2)*NT_+2] + a3*lwL[(d0+3)*NT_+2];
    #pragma unroll
    for (int s = 1; s < 32; s <<= 1) {
        s0 += __shfl_xor(s0, s, 32);
        s1 += __shfl_xor(s1, s, 32);
        s2 += __shfl_xor(s2, s, 32);
    }
    if (l < NT_) {
        float lg = (l == 0) ? s0 : (l == 1) ? s1 : s2;
        lg += lwL[FC_*NT_ + l];
        float sg = 1.f / (1.f + expf(-lg));
        out[(size_t)item*NT_ + l] = sg * sorted_score[item];
    }
}

extern "C" void kernel_launch(void* const* d_in, const int* in_sizes, int n_in,
                              void* d_out, int out_size, void* d_ws, size_t ws_size,
                              hipStream_t stream) {
    (void)in_sizes; (void)n_in; (void)out_size; (void)ws_size;
    const float* roi_feat = (const float*)d_in[0];
    const float* scores   = (const float*)d_in[1];
    const float* pdeltas  = (const float*)d_in[2];
    const float* pboxes   = (const float*)d_in[3];
    const float* roi_w    = (const float*)d_in[4];
    const float* roi_b    = (const float*)d_in[5];
    const float* rank_w   = (const float*)d_in[6];
    const float* rank_b   = (const float*)d_in[7];
    const float* logit_w  = (const float*)d_in[8];
    const float* logit_b  = (const float*)d_in[9];
    const float* pos_w    = (const float*)d_in[10];
    const float* pos_b    = (const float*)d_in[11];
    const float* q_w      = (const float*)d_in[12];
    const float* q_b      = (const float*)d_in[13];
    const float* k_w      = (const float*)d_in[14];
    const float* k_b      = (const float*)d_in[15];
    const float* out_w    = (const float*)d_in[16];
    const float* out_b    = (const float*)d_in[17];
    float* ws = (float*)d_ws;

    float* roiP         = ws + O_ROIP;
    float* rankP        = ws + O_RANKP;
    int*   rank_idx     = (int*)(ws + O_RANKIDX);
    float* sorted_score = ws + O_SSCORE;
    float* sorted_boxes = ws + O_SBOX;
    float* emb_feat     = ws + O_EMB;
    float* att          = ws + O_ATT;
    unsigned short* lwb = (unsigned short*)(ws + O_LW);

    k_embed<<<dim3(144), dim3(256), 0, stream>>>(roi_feat, roi_w, roi_b, rank_w, rank_b,
                                                 roiP, rankP);
    k_topk<<<dim3(B_*C_), dim3(512), 0, stream>>>(scores, rank_idx, sorted_score);
    k_gather<<<dim3(B_*FN_*C_/8), dim3(256), 0, stream>>>(rank_idx, roiP, rankP,
                                                          pdeltas, pboxes, emb_feat, sorted_boxes);
    k_pos2<<<dim3(B_*C_*64), dim3(256), 0, stream>>>(sorted_boxes, pos_w, pos_b, lwb);
    k_attn<<<dim3(B_*C_*G_), dim3(1024), 0, stream>>>(emb_feat, q_w, q_b, k_w, k_b,
                                                      out_w, out_b, lwb, att);
    k_final<<<dim3(B_*FN_*C_/8), dim3(256), 0, stream>>>(emb_feat, att, logit_w, logit_b,
                                                         sorted_score, d_out ? (float*)d_out : nullptr);
}